// Round 2
// baseline (39719.901 us; speedup 1.0000x reference)
//
#include <hip/hip_runtime.h>

// ---------------------------------------------------------------------------
// BiLSTM + CRF loss, MI355X — round 2.
// Fence-free, barrier-free LSTM recurrence: h values published as
// (tag<<16 | bf16) words via relaxed agent-scope atomic stores; consumers
// spin on per-word tags. 32 WGs total (16 per direction), weights
// register-resident as MFMA A-fragments, cell state in registers, zero LDS.
// ---------------------------------------------------------------------------

constexpr int B_ = 32, T_ = 2048, D_ = 256, H_ = 256, K_ = 8;

typedef __bf16 v8bf __attribute__((ext_vector_type(8)));
typedef float  v4f  __attribute__((ext_vector_type(4)));
typedef unsigned int u32;
typedef unsigned long long u64;

union Frag { v8bf v; u32 u[4]; };

__device__ __forceinline__ float sigm(float x)   { return 1.f / (1.f + __expf(-x)); }
__device__ __forceinline__ float tanh_f(float x) { float e = __expf(2.f * x); return 1.f - 2.f / (e + 1.f); }

// unpack a u64 = two tagged words -> packed 2xbf16, check both tags
__device__ __forceinline__ bool take2(u64 q, u32 target, u32& word) {
  u32 lo = (u32)q, hi = (u32)(q >> 32);
  word = (lo & 0xffffu) | (hi << 16);
  return ((lo >> 16) == target) & ((hi >> 16) == target);
}

// hex layout: [dir][parity][batch 32][helem 256] u32 words
__global__ __launch_bounds__(256, 1) void lstm_pass(
    const float* __restrict__ sent, const int* __restrict__ lengths,
    const float* __restrict__ w_ih_f, const float* __restrict__ w_hh_f,
    const float* __restrict__ b_ih_f, const float* __restrict__ b_hh_f,
    const float* __restrict__ w_ih_b, const float* __restrict__ w_hh_b,
    const float* __restrict__ b_ih_b, const float* __restrict__ b_hh_b,
    const float* __restrict__ w_tag,
    u32* hex, float* emisF, float* emisB)
{
  const int blk  = blockIdx.x;
  const int d    = blk >> 4;          // direction
  const int j    = blk & 15;          // WG within dir: owns h-elems [16j,16j+16)
  const int tid  = threadIdx.x;
  const int lane = tid & 63;
  const int w    = tid >> 6;          // wave: owns h-elems [16j+4w, 16j+4w+4)
  const int quad = lane >> 4;
  const int fm   = lane & 15;
  const int n    = fm;                // batch within group

  const float* w_ih = d ? w_ih_b : w_ih_f;
  const float* w_hh = d ? w_hh_b : w_hh_f;
  const float* b_ih = d ? b_ih_b : b_ih_f;
  const float* b_hh = d ? b_hh_b : b_hh_f;

  const int e0 = j * 16 + w * 4 + quad;                    // lane's owned h-elem
  const int gr = (fm & 3) * 256 + (j * 16 + w * 4 + (fm >> 2)); // A-frag gate row

  // weight A-fragments: kslices 0..7 = w_ih (k=0..255), 8..15 = w_hh (k=0..255)
  v8bf af[16];
  #pragma unroll
  for (int s = 0; s < 16; ++s) {
    const float* src = (s < 8) ? (w_ih + (size_t)gr * 256 + 32 * s + 8 * quad)
                               : (w_hh + (size_t)gr * 256 + 32 * (s - 8) + 8 * quad);
    #pragma unroll
    for (int e = 0; e < 8; ++e) af[s][e] = (__bf16)src[e];
  }
  float biasv[4];
  #pragma unroll
  for (int r = 0; r < 4; ++r) biasv[r] = b_ih[r * 256 + e0] + b_hh[r * 256 + e0];

  // emission duty: WG0, waves 0/1 (wave = batch group)
  const bool emw = (j == 0) && (w < 2);
  v8bf ema[8];
  if (emw) {
    #pragma unroll
    for (int hs = 0; hs < 8; ++hs)
      #pragma unroll
      for (int e = 0; e < 8; ++e)
        ema[hs][e] = (fm < 8) ? (__bf16)w_tag[(size_t)fm * 512 + d * 256 + 32 * hs + 8 * quad + e]
                              : (__bf16)0.f;
  }

  const int L0 = lengths[n], L1 = lengths[n + 16];
  int Lmax = 0;
  for (int i = 0; i < 32; ++i) Lmax = max(Lmax, lengths[i]);

  u32* hexd = hex + (size_t)d * 2 * 32 * 256;
  float c0 = 0.f, c1 = 0.f;

  for (int t = 0; t < Lmax; ++t) {
    // ---- x-part MFMAs (cached loads; independent of other WGs)
    v4f acc0 = {0.f, 0.f, 0.f, 0.f}, acc1 = {0.f, 0.f, 0.f, 0.f};
    {
      int tx0 = d ? max(L0 - 1 - t, 0) : t;
      int tx1 = d ? max(L1 - 1 - t, 0) : t;
      const float* xb0 = sent + ((size_t)n * T_ + tx0) * D_ + 8 * quad;
      const float* xb1 = sent + ((size_t)(n + 16) * T_ + tx1) * D_ + 8 * quad;
      #pragma unroll
      for (int s = 0; s < 8; ++s) {
        float4 a0 = *(const float4*)(xb0 + 32 * s);
        float4 a1 = *(const float4*)(xb0 + 32 * s + 4);
        float4 b0 = *(const float4*)(xb1 + 32 * s);
        float4 b1 = *(const float4*)(xb1 + 32 * s + 4);
        v8bf x0, x1;
        x0[0]=(__bf16)a0.x; x0[1]=(__bf16)a0.y; x0[2]=(__bf16)a0.z; x0[3]=(__bf16)a0.w;
        x0[4]=(__bf16)a1.x; x0[5]=(__bf16)a1.y; x0[6]=(__bf16)a1.z; x0[7]=(__bf16)a1.w;
        x1[0]=(__bf16)b0.x; x1[1]=(__bf16)b0.y; x1[2]=(__bf16)b0.z; x1[3]=(__bf16)b0.w;
        x1[4]=(__bf16)b1.x; x1[5]=(__bf16)b1.y; x1[6]=(__bf16)b1.z; x1[7]=(__bf16)b1.w;
        acc0 = __builtin_amdgcn_mfma_f32_16x16x32_bf16(af[s], x0, acc0, 0, 0, 0);
        acc1 = __builtin_amdgcn_mfma_f32_16x16x32_bf16(af[s], x1, acc1, 0, 0, 0);
      }
    }

    // ---- h-part: tag-validated coherent loads + MFMAs
    if (t > 0) {
      const u32 target = (u32)t;
      const u32* hb = hexd + (size_t)((t + 1) & 1) * 32 * 256;
      const u32* r0 = hb + n * 256 + 8 * quad;
      const u32* r1 = hb + (n + 16) * 256 + 8 * quad;
      Frag hf0[8], hf1[8];
      bool ok = false;
      for (int tries = 0; tries < (1 << 14); ++tries) {
        ok = true;
        #pragma unroll
        for (int hs = 0; hs < 8; ++hs) {
          const u64* p0 = (const u64*)(r0 + 32 * hs);
          const u64* p1 = (const u64*)(r1 + 32 * hs);
          #pragma unroll
          for (int qq = 0; qq < 4; ++qq) {
            u64 q0 = __hip_atomic_load(p0 + qq, __ATOMIC_RELAXED, __HIP_MEMORY_SCOPE_AGENT);
            u64 q1 = __hip_atomic_load(p1 + qq, __ATOMIC_RELAXED, __HIP_MEMORY_SCOPE_AGENT);
            ok &= take2(q0, target, hf0[hs].u[qq]);
            ok &= take2(q1, target, hf1[hs].u[qq]);
          }
        }
        if (!__any((int)(!ok))) break;
        __builtin_amdgcn_s_sleep(1);
      }
      #pragma unroll
      for (int hs = 0; hs < 8; ++hs) {
        acc0 = __builtin_amdgcn_mfma_f32_16x16x32_bf16(af[8 + hs], hf0[hs].v, acc0, 0, 0, 0);
        acc1 = __builtin_amdgcn_mfma_f32_16x16x32_bf16(af[8 + hs], hf1[hs].v, acc1, 0, 0, 0);
      }
      // emission for step t-1 (reuses h B-frags just loaded)
      if (emw) {
        v4f em = {0.f, 0.f, 0.f, 0.f};
        #pragma unroll
        for (int hs = 0; hs < 8; ++hs)
          em = __builtin_amdgcn_mfma_f32_16x16x32_bf16(ema[hs], (w ? hf1[hs].v : hf0[hs].v), em, 0, 0, 0);
        int Lb = w ? L1 : L0, s = t - 1;
        if (s < Lb && quad < 2) {
          int pos = d ? (Lb - 1 - s) : s;
          float* dst = (d ? emisB : emisF) + ((size_t)(n + 16 * w) * T_ + pos) * K_ + 4 * quad;
          *(float4*)dst = make_float4(em[0], em[1], em[2], em[3]);
        }
      }
    }

    // ---- cell update (per lane: one h-elem, two batches) + publish
    {
      u32* st = hexd + (size_t)(t & 1) * 32 * 256;
      float gi = acc0[0] + biasv[0], gf = acc0[1] + biasv[1];
      float gg = acc0[2] + biasv[2], go = acc0[3] + biasv[3];
      c0 = sigm(gf) * c0 + sigm(gi) * tanh_f(gg);
      float h = sigm(go) * tanh_f(c0);
      u32 word = ((u32)(t + 1) << 16) | (u32)__builtin_bit_cast(unsigned short, (__bf16)h);
      __hip_atomic_store(st + n * 256 + e0, word, __ATOMIC_RELAXED, __HIP_MEMORY_SCOPE_AGENT);

      gi = acc1[0] + biasv[0]; gf = acc1[1] + biasv[1];
      gg = acc1[2] + biasv[2]; go = acc1[3] + biasv[3];
      c1 = sigm(gf) * c1 + sigm(gi) * tanh_f(gg);
      h = sigm(go) * tanh_f(c1);
      word = ((u32)(t + 1) << 16) | (u32)__builtin_bit_cast(unsigned short, (__bf16)h);
      __hip_atomic_store(st + (n + 16) * 256 + e0, word, __ATOMIC_RELAXED, __HIP_MEMORY_SCOPE_AGENT);
    }
  }

  // ---- tail emission for s = Lmax-1
  if (emw && Lmax > 0) {
    const u32 target = (u32)Lmax;
    const u32* hb = hexd + (size_t)((Lmax + 1) & 1) * 32 * 256;
    const u32* r = hb + (n + 16 * w) * 256 + 8 * quad;
    Frag hf[8];
    bool ok = false;
    for (int tries = 0; tries < (1 << 14); ++tries) {
      ok = true;
      #pragma unroll
      for (int hs = 0; hs < 8; ++hs) {
        const u64* p = (const u64*)(r + 32 * hs);
        #pragma unroll
        for (int qq = 0; qq < 4; ++qq) {
          u64 q = __hip_atomic_load(p + qq, __ATOMIC_RELAXED, __HIP_MEMORY_SCOPE_AGENT);
          ok &= take2(q, target, hf[hs].u[qq]);
        }
      }
      if (!__any((int)(!ok))) break;
      __builtin_amdgcn_s_sleep(1);
    }
    v4f em = {0.f, 0.f, 0.f, 0.f};
    #pragma unroll
    for (int hs = 0; hs < 8; ++hs)
      em = __builtin_amdgcn_mfma_f32_16x16x32_bf16(ema[hs], hf[hs].v, em, 0, 0, 0);
    int Lb = w ? L1 : L0, s = Lmax - 1;
    if (s < Lb && quad < 2) {
      int pos = d ? (Lb - 1 - s) : s;
      float* dst = (d ? emisB : emisF) + ((size_t)(n + 16 * w) * T_ + pos) * K_ + 4 * quad;
      *(float4*)dst = make_float4(em[0], em[1], em[2], em[3]);
    }
  }
}

// CRF: one wave per batch; lanes = (j = l>>3 prev-state, k = l&7 next-state).
// Emissions staged through LDS in double-buffered 64-step chunks.
__global__ __launch_bounds__(64) void crf_pass(
    const int* __restrict__ lengths, const int* __restrict__ tags,
    const float* __restrict__ b_tag, const float* __restrict__ start_trans,
    const float* __restrict__ end_trans, const float* __restrict__ trans,
    const float* __restrict__ emisF, const float* __restrict__ emisB, float* out)
{
  int b = blockIdx.x;
  int l = threadIdx.x;
  int L = lengths[b];
  int j = l >> 3, k = l & 7;
  float trl = trans[j * 8 + k];
  float btk = b_tag[k];
  const float* eF = emisF + (size_t)b * T_ * K_;
  const float* eB = emisB + (size_t)b * T_ * K_;

  __shared__ __align__(16) float buf[2][64][16];   // [chunk parity][step][eF 0..7 | eB 8..15]
  const float4* pF = (const float4*)eF;
  const float4* pB = (const float4*)eB;
  #pragma unroll
  for (int i = 0; i < 2; ++i) {
    int f = l + 64 * i, st = f >> 1, hf = (f & 1) * 4;
    *(float4*)&buf[0][st][hf]     = pF[f];
    *(float4*)&buf[0][st][8 + hf] = pB[f];
  }
  __syncthreads();

  float score = start_trans[j] + buf[0][0][j] + buf[0][0][8 + j] + b_tag[j];
  int nch = (L + 63) >> 6;
  for (int c = 0; c < nch; ++c) {
    float4 preF[2], preB[2];
    bool more = (c + 1 < nch);
    if (more) {
      #pragma unroll
      for (int i = 0; i < 2; ++i) {
        preF[i] = pF[128 * (c + 1) + l + 64 * i];
        preB[i] = pB[128 * (c + 1) + l + 64 * i];
      }
    }
    int cur = c & 1;
    int tend = min(64, L - 64 * c);
    for (int tt = (c == 0 ? 1 : 0); tt < tend; ++tt) {
      float e = buf[cur][tt][k] + buf[cur][tt][8 + k] + btk;
      float v = score + trl;
      float m = fmaxf(v, __shfl_xor(v, 8)); m = fmaxf(m, __shfl_xor(m, 16)); m = fmaxf(m, __shfl_xor(m, 32));
      float p = __expf(v - m);
      p += __shfl_xor(p, 8); p += __shfl_xor(p, 16); p += __shfl_xor(p, 32);
      score = __shfl(m + __logf(p) + e, j);
    }
    if (more) {
      __syncthreads();
      #pragma unroll
      for (int i = 0; i < 2; ++i) {
        int f = l + 64 * i, st = f >> 1, hf = (f & 1) * 4;
        *(float4*)&buf[cur ^ 1][st][hf]     = preF[i];
        *(float4*)&buf[cur ^ 1][st][8 + hf] = preB[i];
      }
      __syncthreads();
    }
  }

  // logZ
  float v = score + end_trans[j];
  float m = fmaxf(v, __shfl_xor(v, 8)); m = fmaxf(m, __shfl_xor(m, 16)); m = fmaxf(m, __shfl_xor(m, 32));
  float p = __expf(v - m);
  p += __shfl_xor(p, 8); p += __shfl_xor(p, 16); p += __shfl_xor(p, 32);
  float logZ = m + __logf(p);

  // numerator (lane-strided over t)
  const int* tg = tags + (size_t)b * T_;
  float nsum = 0.f;
  for (int t = l; t < L; t += 64) {
    int tt = tg[t];
    float e = eF[t * 8 + tt] + eB[t * 8 + tt] + b_tag[tt];
    float tr = (t > 0) ? trans[tg[t - 1] * 8 + tt] : 0.f;
    nsum += e + tr;
  }
  nsum += __shfl_xor(nsum, 1);  nsum += __shfl_xor(nsum, 2);  nsum += __shfl_xor(nsum, 4);
  nsum += __shfl_xor(nsum, 8);  nsum += __shfl_xor(nsum, 16); nsum += __shfl_xor(nsum, 32);
  if (l == 0) {
    float num = nsum + start_trans[tg[0]] + end_trans[tg[L - 1]];
    atomicAdd(out, (logZ - num) * (1.f / 32.f));
  }
}

extern "C" void kernel_launch(void* const* d_in, const int* in_sizes, int n_in,
                              void* d_out, int out_size, void* d_ws, size_t ws_size,
                              hipStream_t stream) {
  (void)in_sizes; (void)n_in; (void)out_size; (void)ws_size;
  const float* sent        = (const float*)d_in[0];
  const int*   tags        = (const int*)d_in[1];
  const int*   lengths     = (const int*)d_in[2];
  // d_in[3] = mask (unused)
  const float* w_ih_f      = (const float*)d_in[4];
  const float* w_hh_f      = (const float*)d_in[5];
  const float* b_ih_f      = (const float*)d_in[6];
  const float* b_hh_f      = (const float*)d_in[7];
  const float* w_ih_b      = (const float*)d_in[8];
  const float* w_hh_b      = (const float*)d_in[9];
  const float* b_ih_b      = (const float*)d_in[10];
  const float* b_hh_b      = (const float*)d_in[11];
  const float* w_tag       = (const float*)d_in[12];
  const float* b_tag       = (const float*)d_in[13];
  const float* start_trans = (const float*)d_in[14];
  const float* end_trans   = (const float*)d_in[15];
  const float* trans       = (const float*)d_in[16];

  char* ws = (char*)d_ws;
  u32*   hex   = (u32*)ws;                          // 128 KB (self-validating tags; no init needed)
  float* emisF = (float*)(ws + (size_t)(1 << 20));  // 2 MB
  float* emisB = (float*)(ws + (size_t)3 * (1 << 20));

  hipMemsetAsync(d_out, 0, sizeof(float), stream);
  lstm_pass<<<32, 256, 0, stream>>>(sent, lengths, w_ih_f, w_hh_f, b_ih_f, b_hh_f,
                                    w_ih_b, w_hh_b, b_ih_b, b_hh_b, w_tag,
                                    hex, emisF, emisB);
  crf_pass<<<32, 64, 0, stream>>>(lengths, tags, b_tag, start_trans, end_trans, trans,
                                  emisF, emisB, (float*)d_out);
}

// Round 3
// 25414.206 us; speedup vs baseline: 1.5629x; 1.5629x over previous
//
#include <hip/hip_runtime.h>

// ---------------------------------------------------------------------------
// BiLSTM + CRF loss, MI355X — round 3.
// 16 persistent WGs; 4 independent recurrence slots (2 dirs x 2 batch-groups)
// processed round-robin so cross-WG h propagation is hidden by other slots'
// compute. h exchanged as (tag<<16 | bf16) words, per-thread independent spin,
// single LDS staging per round (no redundant cross-wave/cross-WG polling).
// ---------------------------------------------------------------------------

constexpr int T_ = 2048, D_ = 256, K_ = 8;

typedef __bf16 v8bf __attribute__((ext_vector_type(8)));
typedef float  v4f  __attribute__((ext_vector_type(4)));
typedef unsigned int u32;
typedef unsigned long long u64;

__device__ __forceinline__ float sigm(float x)   { return 1.f / (1.f + __expf(-x)); }
__device__ __forceinline__ float tanh_f(float x) { float e = __expf(2.f * x); return 1.f - 2.f / (e + 1.f); }

// hbuf layout: [dir][parity][bg][batch16][elem256] u32 (tag<<16 | bf16)
__device__ __forceinline__ size_t slot_off(int d, int par, int bg) {
  return (((size_t)d * 2 + par) * 2 + bg) * 4096;
}

__global__ __launch_bounds__(256, 1) void lstm_pass(
    const float* __restrict__ sent, const int* __restrict__ lengths,
    const float* __restrict__ w_ih_f, const float* __restrict__ w_hh_f,
    const float* __restrict__ b_ih_f, const float* __restrict__ b_hh_f,
    const float* __restrict__ w_ih_b, const float* __restrict__ w_hh_b,
    const float* __restrict__ b_ih_b, const float* __restrict__ b_hh_b,
    const float* __restrict__ w_tag,
    u32* hbuf, float* emisF, float* emisB)
{
  const int j    = blockIdx.x;        // WG: owns h-elems [16j,16j+16) per dir
  const int tid  = threadIdx.x;
  const int lane = tid & 63;
  const int w    = tid >> 6;          // wave: Mtile = elems [16j+4w, 16j+4w+4)
  const int quad = lane >> 4;
  const int fm   = lane & 15;

  __shared__ __bf16 hlds[16][264];    // staged h  [local batch][elem], +8 pad
  __shared__ __bf16 xlds[16][264];    // staged x
  __shared__ float  wtaglds[2][8][256];
  __shared__ float  empart[4][8];
  __shared__ int    lenlds[32];

  if (tid < 32) lenlds[tid] = lengths[tid];
  for (int idx = tid; idx < 4096; idx += 256) {
    int dd = idx >> 11, kk = (idx >> 8) & 7, e = idx & 255;
    wtaglds[dd][kk][e] = w_tag[(size_t)kk * 512 + dd * 256 + e];
  }
  __syncthreads();

  int Lmax = 0;
  #pragma unroll
  for (int i = 0; i < 32; ++i) Lmax = max(Lmax, lenlds[i]);

  // ---- weight A-fragments, both dirs. Mtile rows rr=fm: gate=rr&3, elemoff=rr>>2
  const int e0 = 16 * j + 4 * w + quad;                       // lane's owned h-elem
  const int gr = (fm & 3) * 256 + (16 * j + 4 * w + (fm >> 2));
  v8bf af[2][16];   // [dir][kslice]: 0..7 = w_ih, 8..15 = w_hh
  float biasv[2][4];
  #pragma unroll
  for (int dd = 0; dd < 2; ++dd) {
    const float* wih = dd ? w_ih_b : w_ih_f;
    const float* whh = dd ? w_hh_b : w_hh_f;
    const float* bih = dd ? b_ih_b : b_ih_f;
    const float* bhh = dd ? b_hh_b : b_hh_f;
    #pragma unroll
    for (int s = 0; s < 16; ++s) {
      const float* src = (s < 8) ? (wih + (size_t)gr * 256 + 32 * s + 8 * quad)
                                 : (whh + (size_t)gr * 256 + 32 * (s - 8) + 8 * quad);
      #pragma unroll
      for (int e = 0; e < 8; ++e) af[dd][s][e] = (__bf16)src[e];
    }
    #pragma unroll
    for (int r = 0; r < 4; ++r) biasv[dd][r] = bih[r * 256 + e0] + bhh[r * 256 + e0];
  }

  float cst[4] = {0.f, 0.f, 0.f, 0.f};   // cell state per slot

  for (int t = 0; t <= Lmax; ++t) {
    #pragma unroll
    for (int s = 0; s < 4; ++s) {
      const int d = s >> 1, bg = s & 1;
      const bool compute = (t < Lmax);

      // phase 1a: issue x global loads (overlap the h spin below)
      float4 xr[4];
      int lb = tid >> 4, cc = tid & 15;
      if (compute) {
        int gb = 16 * bg + lb;
        int Lb = lenlds[gb];
        int tx = d ? max(Lb - 1 - t, 0) : t;
        const float4* xp = (const float4*)(sent + ((size_t)gb * T_ + tx) * D_ + cc * 16);
        xr[0] = xp[0]; xr[1] = xp[1]; xr[2] = xp[2]; xr[3] = xp[3];
      }

      // phase 2: per-thread spin on own 8 tagged u64s of slot's h(t-1) -> LDS
      if (t >= 1) {
        const u64* hp = (const u64*)(hbuf + slot_off(d, (t + 1) & 1, bg));
        const u32 target = (u32)t;
        bool done[8] = {false, false, false, false, false, false, false, false};
        int nleft = 8, guard = 0;
        while (nleft > 0 && guard < (1 << 14)) {
          ++guard;
          u64 q[8];
          #pragma unroll
          for (int ii = 0; ii < 8; ++ii)
            if (!done[ii]) q[ii] = __hip_atomic_load(hp + tid + 256 * ii,
                                     __ATOMIC_RELAXED, __HIP_MEMORY_SCOPE_AGENT);
          #pragma unroll
          for (int ii = 0; ii < 8; ++ii) {
            if (!done[ii]) {
              u64 v = q[ii];
              if (((u32)((v >> 16) & 0xffffu) == target) && ((u32)(v >> 48) == target)) {
                int idx = tid + 256 * ii;
                int b = idx >> 7, ep = (idx & 127) * 2;
                u32 pk = (u32)(v & 0xffffu) | (((u32)(v >> 32) & 0xffffu) << 16);
                *(u32*)&hlds[b][ep] = pk;
                done[ii] = true; --nleft;
              }
            }
          }
          if (nleft) __builtin_amdgcn_s_sleep(1);
        }
      }

      // phase 1b: convert x -> bf16, stage to LDS
      if (compute) {
        const float* xf = (const float*)xr;
        v8bf b0, b1;
        #pragma unroll
        for (int e = 0; e < 8; ++e) { b0[e] = (__bf16)xf[e]; b1[e] = (__bf16)xf[8 + e]; }
        *(v8bf*)&xlds[lb][cc * 16]     = b0;
        *(v8bf*)&xlds[lb][cc * 16 + 8] = b1;
      }
      __syncthreads();   // staging visible

      // phase 3: MFMAs + cell update + publish
      if (compute) {
        v4f acc = {0.f, 0.f, 0.f, 0.f};
        #pragma unroll
        for (int ss = 0; ss < 8; ++ss) {
          v8bf xfr = *(const v8bf*)&xlds[fm][32 * ss + 8 * quad];
          acc = __builtin_amdgcn_mfma_f32_16x16x32_bf16(af[d][ss], xfr, acc, 0, 0, 0);
        }
        if (t >= 1) {
          #pragma unroll
          for (int ss = 0; ss < 8; ++ss) {
            v8bf hfr = *(const v8bf*)&hlds[fm][32 * ss + 8 * quad];
            acc = __builtin_amdgcn_mfma_f32_16x16x32_bf16(af[d][8 + ss], hfr, acc, 0, 0, 0);
          }
        }
        float gi = acc[0] + biasv[d][0], gf = acc[1] + biasv[d][1];
        float gg = acc[2] + biasv[d][2], go = acc[3] + biasv[d][3];
        float c = sigm(gf) * cst[s] + sigm(gi) * tanh_f(gg);
        cst[s] = c;
        float h = sigm(go) * tanh_f(c);
        u32 word = ((u32)(t + 1) << 16) |
                   (u32)__builtin_bit_cast(unsigned short, (__bf16)h);
        u32* st = hbuf + slot_off(d, t & 1, bg);
        __hip_atomic_store(st + fm * 256 + e0, word,
                           __ATOMIC_RELAXED, __HIP_MEMORY_SCOPE_AGENT);
      }

      // phase 4: emission for step t-1, batch (16*bg + j), from staged h
      if (t >= 1) {
        float hval = (float)hlds[j][tid];
        float ev[8];
        #pragma unroll
        for (int k = 0; k < 8; ++k) ev[k] = hval * wtaglds[d][k][tid];
        #pragma unroll
        for (int off = 1; off < 64; off <<= 1)
          #pragma unroll
          for (int k = 0; k < 8; ++k) ev[k] += __shfl_xor(ev[k], off);
        if (lane == 0)
          #pragma unroll
          for (int k = 0; k < 8; ++k) empart[w][k] = ev[k];
      }
      __syncthreads();   // empart visible; also gates next round's LDS writes
      if (t >= 1 && tid < 8) {
        float v = empart[0][tid] + empart[1][tid] + empart[2][tid] + empart[3][tid];
        int gb = 16 * bg + j;
        int Lb = lenlds[gb], stp = t - 1;
        if (stp < Lb) {
          int pos = d ? (Lb - 1 - stp) : stp;
          (d ? emisB : emisF)[((size_t)gb * T_ + pos) * K_ + tid] = v;
        }
      }
    }
  }
}

// CRF: one wave per batch; lanes = (j = l>>3 prev-state, k = l&7 next-state).
__global__ __launch_bounds__(64) void crf_pass(
    const int* __restrict__ lengths, const int* __restrict__ tags,
    const float* __restrict__ b_tag, const float* __restrict__ start_trans,
    const float* __restrict__ end_trans, const float* __restrict__ trans,
    const float* __restrict__ emisF, const float* __restrict__ emisB, float* out)
{
  int b = blockIdx.x;
  int l = threadIdx.x;
  int L = lengths[b];
  int j = l >> 3, k = l & 7;
  float trl = trans[j * 8 + k];
  float btk = b_tag[k];
  const float* eF = emisF + (size_t)b * T_ * K_;
  const float* eB = emisB + (size_t)b * T_ * K_;

  __shared__ __align__(16) float buf[2][64][16];
  const float4* pF = (const float4*)eF;
  const float4* pB = (const float4*)eB;
  #pragma unroll
  for (int i = 0; i < 2; ++i) {
    int f = l + 64 * i, st = f >> 1, hf = (f & 1) * 4;
    *(float4*)&buf[0][st][hf]     = pF[f];
    *(float4*)&buf[0][st][8 + hf] = pB[f];
  }
  __syncthreads();

  float score = start_trans[j] + buf[0][0][j] + buf[0][0][8 + j] + b_tag[j];
  int nch = (L + 63) >> 6;
  for (int c = 0; c < nch; ++c) {
    float4 preF[2], preB[2];
    bool more = (c + 1 < nch);
    if (more) {
      #pragma unroll
      for (int i = 0; i < 2; ++i) {
        preF[i] = pF[128 * (c + 1) + l + 64 * i];
        preB[i] = pB[128 * (c + 1) + l + 64 * i];
      }
    }
    int cur = c & 1;
    int tend = min(64, L - 64 * c);
    for (int tt = (c == 0 ? 1 : 0); tt < tend; ++tt) {
      float e = buf[cur][tt][k] + buf[cur][tt][8 + k] + btk;
      float v = score + trl;
      float m = fmaxf(v, __shfl_xor(v, 8)); m = fmaxf(m, __shfl_xor(m, 16)); m = fmaxf(m, __shfl_xor(m, 32));
      float p = __expf(v - m);
      p += __shfl_xor(p, 8); p += __shfl_xor(p, 16); p += __shfl_xor(p, 32);
      score = __shfl(m + __logf(p) + e, j);
    }
    if (more) {
      __syncthreads();
      #pragma unroll
      for (int i = 0; i < 2; ++i) {
        int f = l + 64 * i, st = f >> 1, hf = (f & 1) * 4;
        *(float4*)&buf[cur ^ 1][st][hf]     = preF[i];
        *(float4*)&buf[cur ^ 1][st][8 + hf] = preB[i];
      }
      __syncthreads();
    }
  }

  float v = score + end_trans[j];
  float m = fmaxf(v, __shfl_xor(v, 8)); m = fmaxf(m, __shfl_xor(m, 16)); m = fmaxf(m, __shfl_xor(m, 32));
  float p = __expf(v - m);
  p += __shfl_xor(p, 8); p += __shfl_xor(p, 16); p += __shfl_xor(p, 32);
  float logZ = m + __logf(p);

  const int* tg = tags + (size_t)b * T_;
  float nsum = 0.f;
  for (int t = l; t < L; t += 64) {
    int tt = tg[t];
    float e = eF[t * 8 + tt] + eB[t * 8 + tt] + b_tag[tt];
    float tr = (t > 0) ? trans[tg[t - 1] * 8 + tt] : 0.f;
    nsum += e + tr;
  }
  nsum += __shfl_xor(nsum, 1);  nsum += __shfl_xor(nsum, 2);  nsum += __shfl_xor(nsum, 4);
  nsum += __shfl_xor(nsum, 8);  nsum += __shfl_xor(nsum, 16); nsum += __shfl_xor(nsum, 32);
  if (l == 0) {
    float num = nsum + start_trans[tg[0]] + end_trans[tg[L - 1]];
    atomicAdd(out, (logZ - num) * (1.f / 32.f));
  }
}

extern "C" void kernel_launch(void* const* d_in, const int* in_sizes, int n_in,
                              void* d_out, int out_size, void* d_ws, size_t ws_size,
                              hipStream_t stream) {
  (void)in_sizes; (void)n_in; (void)out_size; (void)ws_size;
  const float* sent        = (const float*)d_in[0];
  const int*   tags        = (const int*)d_in[1];
  const int*   lengths     = (const int*)d_in[2];
  // d_in[3] = mask (unused)
  const float* w_ih_f      = (const float*)d_in[4];
  const float* w_hh_f      = (const float*)d_in[5];
  const float* b_ih_f      = (const float*)d_in[6];
  const float* b_hh_f      = (const float*)d_in[7];
  const float* w_ih_b      = (const float*)d_in[8];
  const float* w_hh_b      = (const float*)d_in[9];
  const float* b_ih_b      = (const float*)d_in[10];
  const float* b_hh_b      = (const float*)d_in[11];
  const float* w_tag       = (const float*)d_in[12];
  const float* b_tag       = (const float*)d_in[13];
  const float* start_trans = (const float*)d_in[14];
  const float* end_trans   = (const float*)d_in[15];
  const float* trans       = (const float*)d_in[16];

  char* ws = (char*)d_ws;
  u32*   hbuf  = (u32*)ws;                          // 64 KB, self-validating tags
  float* emisF = (float*)(ws + (size_t)(1 << 20));  // 2 MB
  float* emisB = (float*)(ws + (size_t)3 * (1 << 20));

  hipMemsetAsync(d_out, 0, sizeof(float), stream);
  lstm_pass<<<16, 256, 0, stream>>>(sent, lengths, w_ih_f, w_hh_f, b_ih_f, b_hh_f,
                                    w_ih_b, w_hh_b, b_ih_b, b_hh_b, w_tag,
                                    hbuf, emisF, emisB);
  crf_pass<<<32, 64, 0, stream>>>(lengths, tags, b_tag, start_trans, end_trans, trans,
                                  emisF, emisB, (float*)d_out);
}

// Round 5
// 9505.125 us; speedup vs baseline: 4.1788x; 2.6737x over previous
//
#include <hip/hip_runtime.h>

// ---------------------------------------------------------------------------
// BiLSTM + CRF loss, MI355X — round 5 (round 4 + workspace-overlap fix).
// Per-step sync confined to ONE workgroup (LDS barrier). Cross-WG data flow
// only at chunk boundaries via stream-ordered kernel launches:
//   prepack -> { pre_gemm(c) ; lstm_chunk(c) } x nchunks -> crf.
// W_hh register-resident as fp8 MFMA A-fragments (A and B packed with the
// same lane->k map, so the contraction is layout-permutation-safe).
// FIX vs r4: hstate is 32 KB (was 16 -> overlapped cstate; f32 cells read as
// bf16 pairs produced NaN patterns). Layout compacted so CT=16 fits 5 MB.
// ---------------------------------------------------------------------------

constexpr int T_ = 2048, D_ = 256, K_ = 8;

typedef __bf16 v8bf __attribute__((ext_vector_type(8)));
typedef float  v4f  __attribute__((ext_vector_type(4)));
typedef unsigned int u32;
typedef unsigned long long u64;
typedef long long i64;

__device__ __forceinline__ float sigm(float x)   { return 1.f / (1.f + __expf(-x)); }
__device__ __forceinline__ float tanh_f(float x) { float e = __expf(2.f * x); return 1.f - 2.f / (e + 1.f); }

__device__ __forceinline__ u32 pk2bf(float a, float b) {
  union { __bf16 h[2]; u32 u; } x; x.h[0] = (__bf16)a; x.h[1] = (__bf16)b; return x.u;
}
__device__ __forceinline__ float lobf(u32 u) { union { u32 u; __bf16 h[2]; } x; x.u = u; return (float)x.h[0]; }
__device__ __forceinline__ float hibf(u32 u) { union { u32 u; __bf16 h[2]; } x; x.u = u; return (float)x.h[1]; }

// packed row p = 16*mtg + rr, rr = 4*q + r  ->  gate r, h-elem 4*mtg + q
__device__ __forceinline__ int gate_row(int mtg, int rr) {
  return (rr & 3) * 256 + 4 * mtg + (rr >> 2);
}

// ws layout:
//   0x000000 wh8    fp8 w_hh  [d][mtg64][kt8][lane64] u64   512 KB
//   0x080000 wt16   bf16 w_tag frags [d][kt8][lane64] 16B    16 KB
//   0x084000 biasp  f32 [d][1024] permuted                    8 KB
//   0x086000 hstate bf16 [slot4][16][256]                    32 KB   (FIXED)
//   0x08E000 cstate f32 [slot4][512][8]                      64 KB
//   0x100000 emisF  bf16 [32][2048][8]   0x200000 emisB       1 MB each
//   0x300000 pre    bf16 [d][CT][32][1024]                   CT*128 KB

__global__ __launch_bounds__(256) void prepack(
    const float* __restrict__ w_hh_f, const float* __restrict__ w_hh_b,
    const float* __restrict__ b_ih_f, const float* __restrict__ b_hh_f,
    const float* __restrict__ b_ih_b, const float* __restrict__ b_hh_b,
    const float* __restrict__ w_tag,
    u64* wh8, v8bf* wt16, float* biasp, u32* hstate_u, float* cstate)
{
  int gid = blockIdx.x * 256 + threadIdx.x;
  if (gid < 65536) {                      // (a) w_hh -> fp8 frags
    int lane = gid & 63, kt = (gid >> 6) & 7, mtg = (gid >> 9) & 63, d = gid >> 15;
    int rr = lane & 15, q = lane >> 4;
    const float* whh = d ? w_hh_b : w_hh_f;
    const float* src = whh + (size_t)gate_row(mtg, rr) * 256 + 32 * kt + 8 * q;
    u32 lo = __builtin_amdgcn_cvt_pk_fp8_f32(src[0], src[1], 0, false);
    lo = __builtin_amdgcn_cvt_pk_fp8_f32(src[2], src[3], lo, true);
    u32 hi = __builtin_amdgcn_cvt_pk_fp8_f32(src[4], src[5], 0, false);
    hi = __builtin_amdgcn_cvt_pk_fp8_f32(src[6], src[7], hi, true);
    wh8[gid] = ((u64)hi << 32) | lo;
  } else if (gid < 66560) {               // (b) w_tag frags (rows 8..15 zero)
    int g = gid - 65536;
    int lane = g & 63, kt = (g >> 6) & 7, d = (g >> 9) & 1;
    int rr = lane & 15, q = lane >> 4;
    v8bf v;
    #pragma unroll
    for (int e = 0; e < 8; ++e)
      v[e] = (rr < 8) ? (__bf16)w_tag[(size_t)rr * 512 + d * 256 + 32 * kt + 8 * q + e]
                      : (__bf16)0.f;
    wt16[g] = v;
  } else if (gid < 68608) {               // (c) permuted bias
    int g = gid - 66560;
    int p = g & 1023, d = g >> 10;
    int gr = gate_row(p >> 4, p & 15);
    biasp[g] = (d ? b_ih_b[gr] + b_hh_b[gr] : b_ih_f[gr] + b_hh_f[gr]);
  } else if (gid < 76800) {               // (d) zero hstate (32 KB = 8192 u32)
    hstate_u[gid - 68608] = 0u;
  } else if (gid < 93184) {               // (e) zero cstate (64 KB = 16384 f32)
    cstate[gid - 76800] = 0.f;
  }
}

__global__ __launch_bounds__(256, 2) void pre_gemm(
    const float* __restrict__ sent, const int* __restrict__ lengths,
    const float* __restrict__ w_ih_f, const float* __restrict__ w_ih_b,
    const float* __restrict__ biasp,
    __bf16* __restrict__ pre, int t0, int CT, int TT)
{
  const int b = blockIdx.x, d = blockIdx.y;
  const int tg = blockIdx.z >> 2, rg = blockIdx.z & 3;
  const int tid = threadIdx.x, lane = tid & 63, w = tid >> 6;
  const int fm = lane & 15, q = lane >> 4;
  const int NT = TT >> 4;                 // TT is 16 or 32
  const int Lb = lengths[b];
  const float* wih = d ? w_ih_b : w_ih_f;

  __shared__ __bf16 xl[32 * 264];

  // stage x (TT steps x 256 feats) as bf16
  for (int rep = 0; rep < NT; ++rep) {
    int tl = (tid >> 4) + 16 * rep, c16 = (tid & 15) * 16;
    int tglob = t0 + TT * tg + tl;
    int pos = d ? ((tglob < Lb) ? (Lb - 1 - tglob) : tglob) : tglob;
    const float4* xp = (const float4*)(sent + ((size_t)b * T_ + pos) * D_ + c16);
    float4 a0 = xp[0], a1 = xp[1], a2 = xp[2], a3 = xp[3];
    v8bf v0, v1;
    v0[0]=(__bf16)a0.x; v0[1]=(__bf16)a0.y; v0[2]=(__bf16)a0.z; v0[3]=(__bf16)a0.w;
    v0[4]=(__bf16)a1.x; v0[5]=(__bf16)a1.y; v0[6]=(__bf16)a1.z; v0[7]=(__bf16)a1.w;
    v1[0]=(__bf16)a2.x; v1[1]=(__bf16)a2.y; v1[2]=(__bf16)a2.z; v1[3]=(__bf16)a2.w;
    v1[4]=(__bf16)a3.x; v1[5]=(__bf16)a3.y; v1[6]=(__bf16)a3.z; v1[7]=(__bf16)a3.w;
    *(v8bf*)&xl[tl * 264 + c16]     = v0;
    *(v8bf*)&xl[tl * 264 + c16 + 8] = v1;
  }

  // A-frags straight from f32 w_ih (row rr = fm), bias as C init
  v8bf af[4][8];
  v4f acc[4][2];
  #pragma unroll
  for (int mt = 0; mt < 4; ++mt) {
    int mtg = 16 * rg + 4 * w + mt;
    const float* src = wih + (size_t)gate_row(mtg, fm) * 256 + 8 * q;
    #pragma unroll
    for (int kt = 0; kt < 8; ++kt) {
      float4 a = *(const float4*)(src + 32 * kt);
      float4 b2 = *(const float4*)(src + 32 * kt + 4);
      v8bf v;
      v[0]=(__bf16)a.x;  v[1]=(__bf16)a.y;  v[2]=(__bf16)a.z;  v[3]=(__bf16)a.w;
      v[4]=(__bf16)b2.x; v[5]=(__bf16)b2.y; v[6]=(__bf16)b2.z; v[7]=(__bf16)b2.w;
      af[mt][kt] = v;
    }
    float4 bs = *(const float4*)(biasp + d * 1024 + 16 * mtg + 4 * q);
    for (int nt = 0; nt < 2; ++nt) acc[mt][nt] = v4f{bs.x, bs.y, bs.z, bs.w};
  }
  __syncthreads();

  for (int kt = 0; kt < 8; ++kt) {
    for (int nt = 0; nt < NT; ++nt) {
      v8bf bfr = *(const v8bf*)&xl[(nt * 16 + fm) * 264 + 32 * kt + 8 * q];
      #pragma unroll
      for (int mt = 0; mt < 4; ++mt)
        acc[mt][nt] = __builtin_amdgcn_mfma_f32_16x16x32_bf16(af[mt][kt], bfr, acc[mt][nt], 0, 0, 0);
    }
  }

  #pragma unroll
  for (int mt = 0; mt < 4; ++mt) {
    int mtg = 16 * rg + 4 * w + mt;
    for (int nt = 0; nt < NT; ++nt) {
      int tl = TT * tg + nt * 16 + fm;
      uint2 pk;
      pk.x = pk2bf(acc[mt][nt][0], acc[mt][nt][1]);
      pk.y = pk2bf(acc[mt][nt][2], acc[mt][nt][3]);
      size_t off = (((size_t)d * CT + tl) * 32 + b) * 1024 + 16 * mtg + 4 * q;
      *(uint2*)((char*)pre + off * 2) = pk;
    }
  }
}

__global__ __launch_bounds__(512, 2) void lstm_chunk(
    const int* __restrict__ lengths,
    const u64* __restrict__ wh8, const v8bf* __restrict__ wt16,
    __bf16* __restrict__ hstate, float* __restrict__ cstate,
    const __bf16* __restrict__ pre,
    __bf16* __restrict__ emisF, __bf16* __restrict__ emisB, int t0, int CT)
{
  const int s = blockIdx.x, d = s >> 1, bg = s & 1;
  const int tid = threadIdx.x, lane = tid & 63, w = tid >> 6;
  const int fm = lane & 15, q = lane >> 4;
  const int Ln = lengths[bg * 16 + fm];

  int Lmax = 0;
  for (int i = 0; i < 32; ++i) Lmax = max(Lmax, lengths[i]);
  const int t1 = t0 + CT;
  const int tend = min(t1, Lmax);

  __shared__ __align__(8) unsigned char h8l[2][16 * 272];
  __shared__ __align__(16) __bf16 hbfl[2][16 * 264];
  __shared__ v8bf wtl[8][64];

  { int kt = tid >> 6, ln = tid & 63; wtl[kt][ln] = wt16[((size_t)d * 8 + kt) * 64 + ln]; }

  // seed h (parity 1 = (t0-1)&1, t0 even) from hstate
  {
    int off = tid * 8, b = off >> 8, e = off & 255;
    uint4 hv = *(const uint4*)(hstate + (size_t)s * 4096 + off);
    *(uint4*)&hbfl[1][b * 264 + e] = hv;
    float f0 = lobf(hv.x), f1 = hibf(hv.x), f2 = lobf(hv.y), f3 = hibf(hv.y);
    float f4 = lobf(hv.z), f5 = hibf(hv.z), f6 = lobf(hv.w), f7 = hibf(hv.w);
    u32 lo = __builtin_amdgcn_cvt_pk_fp8_f32(f0, f1, 0, false);
    lo = __builtin_amdgcn_cvt_pk_fp8_f32(f2, f3, lo, true);
    u32 hi = __builtin_amdgcn_cvt_pk_fp8_f32(f4, f5, 0, false);
    hi = __builtin_amdgcn_cvt_pk_fp8_f32(f6, f7, hi, true);
    *(u64*)&h8l[1][b * 272 + e] = ((u64)hi << 32) | lo;
  }

  // W_hh fp8 A-frags: 64 u64 = 128 VGPRs
  u64 af[8][8];
  #pragma unroll
  for (int mt = 0; mt < 8; ++mt) {
    int mtg = 8 * w + mt;
    #pragma unroll
    for (int kt = 0; kt < 8; ++kt)
      af[mt][kt] = wh8[((size_t)(d * 64 + mtg) * 8 + kt) * 64 + lane];
  }
  float c8[8];
  #pragma unroll
  for (int mt = 0; mt < 8; ++mt) c8[mt] = cstate[((size_t)s * 512 + tid) * 8 + mt];

  __bf16* emis = d ? emisB : emisF;

  for (int t = t0; t < tend; ++t) {
    __syncthreads();
    const char* preb = (const char*)pre +
        ((((size_t)d * CT + (t - t0)) * 32 + (bg * 16 + fm)) * 1024) * 2;
    uint2 pld[8];
    #pragma unroll
    for (int mt = 0; mt < 8; ++mt)
      pld[mt] = *(const uint2*)(preb + (16 * (8 * w + mt) + 4 * q) * 2);

    const int pp = (t + 1) & 1;
    u64 bf8[8];
    #pragma unroll
    for (int kt = 0; kt < 8; ++kt)
      bf8[kt] = *(const u64*)&h8l[pp][fm * 272 + 32 * kt + 8 * q];

    v4f acc[8];
    #pragma unroll
    for (int mt = 0; mt < 8; ++mt) acc[mt] = v4f{0.f, 0.f, 0.f, 0.f};
    #pragma unroll
    for (int kt = 0; kt < 8; ++kt)
      #pragma unroll
      for (int mt = 0; mt < 8; ++mt)
        acc[mt] = __builtin_amdgcn_mfma_f32_16x16x32_fp8_fp8((i64)af[mt][kt], (i64)bf8[kt], acc[mt], 0, 0, 0);

    // emission for step t-1 (wave 0; bf16 h frags x w_tag)
    if (w == 0) {
      v4f ea = {0.f, 0.f, 0.f, 0.f};
      #pragma unroll
      for (int kt = 0; kt < 8; ++kt) {
        v8bf hb = *(const v8bf*)&hbfl[pp][fm * 264 + 32 * kt + 8 * q];
        ea = __builtin_amdgcn_mfma_f32_16x16x32_bf16(wtl[kt][lane], hb, ea, 0, 0, 0);
      }
      int se = t - 1;
      if (se >= 0 && q < 2 && se < Ln) {
        int pos = d ? (Ln - 1 - se) : se;
        uint2 pk; pk.x = pk2bf(ea[0], ea[1]); pk.y = pk2bf(ea[2], ea[3]);
        *(uint2*)((char*)emis + (((size_t)(bg * 16 + fm) * T_ + pos) * K_ + 4 * q) * 2) = pk;
      }
    }

    // cell update + publish h into parity t&1
    #pragma unroll
    for (int mt = 0; mt < 8; ++mt) {
      float gi = acc[mt][0] + lobf(pld[mt].x);
      float gf = acc[mt][1] + hibf(pld[mt].x);
      float gg = acc[mt][2] + lobf(pld[mt].y);
      float go = acc[mt][3] + hibf(pld[mt].y);
      float c = sigm(gf) * c8[mt] + sigm(gi) * tanh_f(gg);
      c8[mt] = c;
      float h = sigm(go) * tanh_f(c);
      int e = 32 * w + 4 * mt + q;
      hbfl[t & 1][fm * 264 + e] = (__bf16)h;
      h8l[t & 1][fm * 272 + e] =
          (unsigned char)(__builtin_amdgcn_cvt_pk_fp8_f32(h, h, 0, false) & 0xff);
    }
  }

  __syncthreads();
  // flush emission for the final step (chunk containing Lmax only)
  if (t0 < Lmax && Lmax <= t1 && w == 0) {
    const int pp = (tend - 1) & 1;
    v4f ea = {0.f, 0.f, 0.f, 0.f};
    #pragma unroll
    for (int kt = 0; kt < 8; ++kt) {
      v8bf hb = *(const v8bf*)&hbfl[pp][fm * 264 + 32 * kt + 8 * q];
      ea = __builtin_amdgcn_mfma_f32_16x16x32_bf16(wtl[kt][lane], hb, ea, 0, 0, 0);
    }
    int se = tend - 1;
    if (q < 2 && se < Ln) {
      int pos = d ? (Ln - 1 - se) : se;
      uint2 pk; pk.x = pk2bf(ea[0], ea[1]); pk.y = pk2bf(ea[2], ea[3]);
      *(uint2*)((char*)emis + (((size_t)(bg * 16 + fm) * T_ + pos) * K_ + 4 * q) * 2) = pk;
    }
  }
  // save state for the next chunk
  if (tend > t0) {
    #pragma unroll
    for (int mt = 0; mt < 8; ++mt) cstate[((size_t)s * 512 + tid) * 8 + mt] = c8[mt];
    int off = tid * 8, b = off >> 8, e = off & 255;
    uint4 hv = *(const uint4*)&hbfl[(tend + 1) & 1][b * 264 + e];
    *(uint4*)(hstate + (size_t)s * 4096 + off) = hv;
  }
}

// CRF: one wave per batch; lanes = (j = l>>3 prev-state, k = l&7 next-state).
__global__ __launch_bounds__(64) void crf_pass(
    const int* __restrict__ lengths, const int* __restrict__ tags,
    const float* __restrict__ b_tag, const float* __restrict__ start_trans,
    const float* __restrict__ end_trans, const float* __restrict__ trans,
    const __bf16* __restrict__ emisF, const __bf16* __restrict__ emisB, float* out)
{
  int b = blockIdx.x;
  int l = threadIdx.x;
  int L = lengths[b];
  int j = l >> 3, k = l & 7;
  float trl = trans[j * 8 + k];
  float btk = b_tag[k];
  const __bf16* eF = emisF + (size_t)b * T_ * K_;
  const __bf16* eB = emisB + (size_t)b * T_ * K_;
  const uint4* pF = (const uint4*)eF;
  const uint4* pB = (const uint4*)eB;

  __shared__ float buf[2][64][16];
  {
    uint4 uF = pF[l], uB = pB[l];
    float* r = &buf[0][l][0];
    r[0]=lobf(uF.x); r[1]=hibf(uF.x); r[2]=lobf(uF.y); r[3]=hibf(uF.y);
    r[4]=lobf(uF.z); r[5]=hibf(uF.z); r[6]=lobf(uF.w); r[7]=hibf(uF.w);
    r[8]=lobf(uB.x); r[9]=hibf(uB.x); r[10]=lobf(uB.y); r[11]=hibf(uB.y);
    r[12]=lobf(uB.z); r[13]=hibf(uB.z); r[14]=lobf(uB.w); r[15]=hibf(uB.w);
  }
  __syncthreads();

  float score = start_trans[j] + buf[0][0][j] + buf[0][0][8 + j] + b_tag[j];
  int nch = (L + 63) >> 6;
  for (int c = 0; c < nch; ++c) {
    uint4 preF, preB;
    bool more = (c + 1 < nch);
    if (more) { preF = pF[64 * (c + 1) + l]; preB = pB[64 * (c + 1) + l]; }
    int cur = c & 1;
    int tendc = min(64, L - 64 * c);
    for (int tt = (c == 0 ? 1 : 0); tt < tendc; ++tt) {
      float e = buf[cur][tt][k] + buf[cur][tt][8 + k] + btk;
      float v = score + trl;
      float m = fmaxf(v, __shfl_xor(v, 8)); m = fmaxf(m, __shfl_xor(m, 16)); m = fmaxf(m, __shfl_xor(m, 32));
      float p = __expf(v - m);
      p += __shfl_xor(p, 8); p += __shfl_xor(p, 16); p += __shfl_xor(p, 32);
      score = __shfl(m + __logf(p) + e, j);
    }
    if (more) {
      __syncthreads();
      float* r = &buf[cur ^ 1][l][0];
      r[0]=lobf(preF.x); r[1]=hibf(preF.x); r[2]=lobf(preF.y); r[3]=hibf(preF.y);
      r[4]=lobf(preF.z); r[5]=hibf(preF.z); r[6]=lobf(preF.w); r[7]=hibf(preF.w);
      r[8]=lobf(preB.x); r[9]=hibf(preB.x); r[10]=lobf(preB.y); r[11]=hibf(preB.y);
      r[12]=lobf(preB.z); r[13]=hibf(preB.z); r[14]=lobf(preB.w); r[15]=hibf(preB.w);
      __syncthreads();
    }
  }

  float v = score + end_trans[j];
  float m = fmaxf(v, __shfl_xor(v, 8)); m = fmaxf(m, __shfl_xor(m, 16)); m = fmaxf(m, __shfl_xor(m, 32));
  float p = __expf(v - m);
  p += __shfl_xor(p, 8); p += __shfl_xor(p, 16); p += __shfl_xor(p, 32);
  float logZ = m + __logf(p);

  const int* tg = tags + (size_t)b * T_;
  float nsum = 0.f;
  for (int t = l; t < L; t += 64) {
    int tt = tg[t];
    float e = (float)eF[t * 8 + tt] + (float)eB[t * 8 + tt] + b_tag[tt];
    float tr = (t > 0) ? trans[tg[t - 1] * 8 + tt] : 0.f;
    nsum += e + tr;
  }
  nsum += __shfl_xor(nsum, 1);  nsum += __shfl_xor(nsum, 2);  nsum += __shfl_xor(nsum, 4);
  nsum += __shfl_xor(nsum, 8);  nsum += __shfl_xor(nsum, 16); nsum += __shfl_xor(nsum, 32);
  if (l == 0) {
    float num = nsum + start_trans[tg[0]] + end_trans[tg[L - 1]];
    atomicAdd(out, (logZ - num) * (1.f / 32.f));
  }
}

extern "C" void kernel_launch(void* const* d_in, const int* in_sizes, int n_in,
                              void* d_out, int out_size, void* d_ws, size_t ws_size,
                              hipStream_t stream) {
  (void)in_sizes; (void)n_in; (void)out_size;
  const float* sent        = (const float*)d_in[0];
  const int*   tags        = (const int*)d_in[1];
  const int*   lengths     = (const int*)d_in[2];
  // d_in[3] = mask (unused)
  const float* w_ih_f      = (const float*)d_in[4];
  const float* w_hh_f      = (const float*)d_in[5];
  const float* b_ih_f      = (const float*)d_in[6];
  const float* b_hh_f      = (const float*)d_in[7];
  const float* w_ih_b      = (const float*)d_in[8];
  const float* w_hh_b      = (const float*)d_in[9];
  const float* b_ih_b      = (const float*)d_in[10];
  const float* b_hh_b      = (const float*)d_in[11];
  const float* w_tag       = (const float*)d_in[12];
  const float* b_tag       = (const float*)d_in[13];
  const float* start_trans = (const float*)d_in[14];
  const float* end_trans   = (const float*)d_in[15];
  const float* trans       = (const float*)d_in[16];

  char* ws = (char*)d_ws;
  u64*    wh8    = (u64*)(ws + 0x000000);
  v8bf*   wt16   = (v8bf*)(ws + 0x080000);
  float*  biasp  = (float*)(ws + 0x084000);
  __bf16* hstate = (__bf16*)(ws + 0x086000);   // 32 KB (4 slots x 8 KB)
  float*  cstate = (float*)(ws + 0x08E000);    // 64 KB
  __bf16* emisF  = (__bf16*)(ws + 0x100000);
  __bf16* emisB  = (__bf16*)(ws + 0x200000);
  __bf16* pre    = (__bf16*)(ws + 0x300000);

  // pick largest CT whose pre-buffer fits; CT=16 needs 5 MB (proven floor)
  int CT = 16;
  for (int cand : {256, 128, 64, 32}) {
    if ((size_t)0x300000 + (size_t)cand * 131072 <= ws_size) { CT = cand; break; }
  }
  const int TT = (CT >= 32) ? 32 : 16;
  const int nch = T_ / CT;

  hipMemsetAsync(d_out, 0, sizeof(float), stream);
  prepack<<<364, 256, 0, stream>>>(w_hh_f, w_hh_b, b_ih_f, b_hh_f, b_ih_b, b_hh_b,
                                   w_tag, wh8, wt16, biasp, (u32*)hstate, cstate);
  for (int c = 0; c < nch; ++c) {
    dim3 grid(32, 2, (CT / TT) * 4);
    pre_gemm<<<grid, 256, 0, stream>>>(sent, lengths, w_ih_f, w_ih_b, biasp,
                                       pre, c * CT, CT, TT);
    lstm_chunk<<<4, 512, 0, stream>>>(lengths, wh8, wt16, hstate, cstate, pre,
                                      emisF, emisB, c * CT, CT);
  }
  crf_pass<<<32, 64, 0, stream>>>(lengths, tags, b_tag, start_trans, end_trans, trans,
                                  emisF, emisB, (float*)d_out);
}